// Round 6
// baseline (206.067 us; speedup 1.0000x reference)
//
#include <hip/hip_runtime.h>
#include <stdint.h>

#define NN 50000
#define NE 800000
#define D  128
#define CAP 64                            // bucket capacity per node (Poisson(16); P(deg>64)~1e-19)
#define OVF_CAP 131072

// ---------------- ws layout (int offsets) ----------------
// Counters init to -1 via 0xFF memset (slot = atomicAdd()+1). Buckets are
// UNINITIALIZED: gather masks tail entries to 0xFFFFFFFF (NaN weight, hot
// row 0xFFFF), and garbage src never escapes (mask applied at entry level).
#define CNT_OFF     64                    // NN counters
#define OVF_CNT_OFF (CNT_OFF + NN)        // 50064
#define OVF_OFF     (OVF_CNT_OFF + 4)     // 50068: OVF_CAP pairs (dst, entry)
#define BKT_OFF     312320                // NN*CAP packed entries: (w_fp16<<16)|src
#define XH_OFF      (BKT_OFF + NN * CAP)  // 3512320: x as fp16 pairs; 65536 logical rows
#define WH_OFF      (XH_OFF + 65536 * (D / 2))      // 7706624: w1+w2 fp16
// total high-water: 7,723,008 ints = 30.9 MB (< 32.4 MB proven available)

#define HSTRIDE 136                       // LDS row stride in ushorts (272 B, 2-way banks = free)
#define SLOTS   24                        // staged row-gathers per node (fixed, unrolled)
#define WLDS    (SLOTS * 256 + 1024)      // per-wave LDS: 24 value rows + 4 bucket rows

// fused prep+fill block ranges
#define FILL_BLKS 3125                    // NE/256 (1 edge/thread; atomic-throughput bound)
#define PX_BLKS   6250                    // NN*D/1024
#define PW_BLKS   32

typedef _Float16 half8 __attribute__((ext_vector_type(8)));
typedef __attribute__((ext_vector_type(4))) float float4v;

// ---------------- dtype helpers ----------------
__device__ __forceinline__ float b2f(uint16_t u) {
    union { uint32_t u; float f; } v; v.u = ((uint32_t)u) << 16; return v.f;
}
__device__ __forceinline__ uint16_t f2b(float f) {
    union { float f; uint32_t u; } v; v.f = f;
    uint32_t r = v.u + 0x7fffu + ((v.u >> 16) & 1u);   // RNE
    return (uint16_t)(r >> 16);
}
__device__ __forceinline__ ushort f2h(float f) {
    union { _Float16 h; ushort u; } v; v.h = (_Float16)f; return v.u;   // v_cvt_f16_f32 (RNE)
}
__device__ __forceinline__ float h2f(ushort u) {
    union { ushort u; _Float16 h; } v; v.u = u; return (float)v.h;
}

// async global->LDS. 16 B per lane: LDS dest = uniform base + lane*16 (1 KB
// = four 256 B rows); global src is per-lane. 4x fewer address slots than
// the 4 B variant for the same bytes. Counts in vmcnt.
__device__ __forceinline__ void gload_lds16(const void* g, void* l) {
    __builtin_amdgcn_global_load_lds(
        (const __attribute__((address_space(1))) void*)g,
        (__attribute__((address_space(3))) void*)l, 16, 0, 0);
}

// ---------------- per-block inline dtype probe (load-bearing; rounds 2-9) ----------------
__device__ __forceinline__ void block_probe(const uint16_t* __restrict__ xraw,
                                            const int* __restrict__ eraw,
                                            int* sflags) {
    int t = threadIdx.x;
    if (t < 64) {                                   // wave 0 only
        float v0 = b2f(xraw[2 * t]);
        float v1 = b2f(xraw[2 * t + 1]);
        int bad = (!(v0 > -1e4f && v0 < 1e4f)) || (!(v1 > -1e4f && v1 < 1e4f));
        unsigned long long bm = __ballot(bad);
        int nz = (t < 32) ? (eraw[2 * t + 1] != 0) : 0;
        unsigned long long im = __ballot(nz);
        if (t == 0) { sflags[0] = bm ? 1 : 0; sflags[1] = im ? 0 : 1; }
    }
    __syncthreads();
}

// ---------------- fused fill + prep_x + prep_w (unchanged; ±10% noise band) ----------------
__global__ __launch_bounds__(256) void prep_fill_kernel(
    const uint16_t* __restrict__ xraw,
    const int*      __restrict__ eraw,
    const uint16_t* __restrict__ ewraw,
    const uint16_t* __restrict__ w1raw,
    const uint16_t* __restrict__ w2raw,
    int* __restrict__ ws)
{
    __shared__ int sflags[2];
    block_probe(xraw, eraw, sflags);
    const int f32 = sflags[0], i64 = sflags[1];

    int bid = blockIdx.x;
    if (bid < FILL_BLKS) {
        // ---- edge fill: one packed 4 B entry per edge ----
        int e = bid * 256 + threadIdx.x;
        int src, dst;
        if (i64) {
            const long long* e64 = (const long long*)eraw;
            src = (int)e64[e];
            dst = (int)e64[NE + e];
        } else {
            src = eraw[e];
            dst = eraw[NE + e];
        }
        if ((unsigned)src >= NN || (unsigned)dst >= NN) return;
        uint w = f32 ? (uint)f2h(((const float*)ewraw)[e]) : (uint)f2h(b2f(ewraw[e]));
        uint entry = (w << 16) | (uint)src;
        int slot = atomicAdd(ws + CNT_OFF + dst, 1) + 1;     // counter starts at -1
        if (slot < CAP) {
            ((uint*)(ws + BKT_OFF))[(size_t)dst * CAP + slot] = entry;
        } else {
            int o = atomicAdd(ws + OVF_CNT_OFF, 1) + 1;      // starts at -1
            if (o < OVF_CAP) {
                ws[OVF_OFF + 2 * o]     = dst;
                ws[OVF_OFF + 2 * o + 1] = (int)entry;
            }
        }
    } else if (bid < FILL_BLKS + PX_BLKS) {
        // ---- x -> fp16 table ----
        int i4 = ((bid - FILL_BLKS) * 256 + threadIdx.x) * 4;   // covers NN*D exactly
        ushort* dst = (ushort*)(ws + XH_OFF);
        if (f32) {
            float4 v = *(const float4*)((const float*)xraw + i4);
            ushort4 o; o.x = f2h(v.x); o.y = f2h(v.y); o.z = f2h(v.z); o.w = f2h(v.w);
            *(ushort4*)(dst + i4) = o;
        } else {
            ushort4 v = *(const ushort4*)(xraw + i4);
            ushort4 o; o.x = f2h(b2f(v.x)); o.y = f2h(b2f(v.y));
            o.z = f2h(b2f(v.z)); o.w = f2h(b2f(v.w));
            *(ushort4*)(dst + i4) = o;
        }
    } else {
        // ---- w1,w2 -> fp16 table ----
        int i4 = ((bid - FILL_BLKS - PX_BLKS) * 256 + threadIdx.x) * 4; // 0..32764
        const uint16_t* src = (i4 < 16384) ? w1raw : w2raw;
        int off = i4 & 16383;
        ushort* dst = (ushort*)(ws + WH_OFF);
        if (f32) {
            float4 v = *(const float4*)((const float*)src + off);
            ushort4 o; o.x = f2h(v.x); o.y = f2h(v.y); o.z = f2h(v.z); o.w = f2h(v.w);
            *(ushort4*)(dst + i4) = o;
        } else {
            ushort4 v = *(const ushort4*)(src + off);
            ushort4 o; o.x = f2h(b2f(v.x)); o.y = f2h(b2f(v.y));
            o.z = f2h(b2f(v.z)); o.w = f2h(b2f(v.w));
            *(ushort4*)(dst + i4) = o;
        }
    }
}

// ---------------- fused gather-max + MFMA MLP ----------------
// 16 nodes/block, 4 waves. Gather via 16 B/lane global_load_lds: one
// instruction stages FOUR 256 B rows (lane group g=lane>>4 covers row
// 4u+g; per-lane src = xrow[entry] + (lane&15)*16; LDS dest linear).
// 6 instructions/node instead of 24 -> 4x fewer address slots through the
// TA (the hypothesized wall). Per-lane entries come from a 16-lane-
// broadcast ds_read of the staged bucket row. Counted vmcnt(3) overlaps
// the first-half consume with the second half's flight. Tails are masked
// to 0xFFFFFFFF (NaN weight, hot row). hl overlays the gather buffer.
__global__ __launch_bounds__(256, 4) void gmlp_kernel(
    const uint16_t* __restrict__ xraw,
    const int*      __restrict__ eraw,
    const uint16_t* __restrict__ b1raw,
    const uint16_t* __restrict__ b2raw,
    const uint16_t* __restrict__ epsraw,
    const int* __restrict__ ws,
    uint16_t* __restrict__ outraw)
{
    __shared__ char smem[4][WLDS];              // per-wave: [0,6144) value rows, [6144,7168) bucket rows
    __shared__ uint tl[16 * (HSTRIDE / 2)];     // t tile, 68 uints/row
    __shared__ int  sflags[2];
    ushort* hl = (ushort*)&smem[0][0];          // hidden tile overlay (post-sync)

    const int tid  = threadIdx.x;
    const int wave = tid >> 6;
    const int lane = tid & 63;
    const int m    = lane & 15;
    const int quad = lane >> 4;
    const int node0 = blockIdx.x * 16;

    const ushort* w1h = (const ushort*)(ws + WH_OFF);
    const ushort* w2h = w1h + 16384;
    const uint*   xh  = (const uint*)(ws + XH_OFF);
    const char*   xhb = (const char*)xh;
    const uint*   bkt = (const uint*)(ws + BKT_OFF);
    const uint    lane4 = (uint)lane * 4;
    const uint    sub16 = (uint)(lane & 15) * 16;  // byte offset within a row for grouped staging
    char*         wbuf  = smem[wave];

    // stage the wave's 4 bucket rows (4 x 256 B, contiguous in global) with
    // ONE 16 B/lane DMA: dest = wbuf+SLOTS*256 .. +1024
    gload_lds16((const char*)(bkt + (size_t)(node0 + wave * 4) * CAP) + (uint)lane * 16,
                wbuf + SLOTS * 256);

    // per-node degree + self-row prefetch (independent loads)
    int deg[4];
    uint xv[4];
    #pragma unroll
    for (int j = 0; j < 4; ++j) {
        deg[j] = ws[CNT_OFF + node0 + wave * 4 + j] + 1;     // counter = deg-1
        xv[j]  = xh[(size_t)(node0 + wave * 4 + j) * 64 + lane];
    }

    block_probe(xraw, eraw, sflags);
    const int f32 = sflags[0];
    const float eps1 = 1.0f + (f32 ? ((const float*)epsraw)[0] : b2f(epsraw[0]));

    asm volatile("s_waitcnt vmcnt(0)" ::: "memory");         // bucket rows in LDS

    #pragma unroll
    for (int j = 0; j < 4; ++j) {
        int nl = wave * 4 + j;
        int n  = node0 + nl;
        int cnt = (deg[j] < CAP) ? deg[j] : CAP;
        const uint* ewp = (const uint*)(wbuf + SLOTS * 256 + j * 256);

        // prior node's ds_reads must be done before DMA re-writes the slots
        asm volatile("s_waitcnt lgkmcnt(0)" ::: "memory");

        // issue: 6 grouped stages; lane group (lane>>4) covers row 4g+grp.
        // entry via 16-lane-broadcast ds_read; tail -> hot row + NaN weight.
        #pragma unroll
        for (int g = 0; g < SLOTS / 4; ++g) {
            uint slot = (uint)(g * 4) + (uint)(lane >> 4);
            uint e0 = ewp[slot];                             // broadcast ds_read
            e0 = (slot < (uint)cnt) ? e0 : 0xffffffffu;
            gload_lds16(xhb + ((e0 & 0xffffu) << 8) + sub16, wbuf + g * 1024);
        }

        uint mm[4] = {~0u, ~0u, ~0u, ~0u};                   // packed fp16 NaN,NaN

        // first half: rows 0..11 (groups 0..2) after vmcnt(3)
        asm volatile("s_waitcnt vmcnt(3)" ::: "memory");
        #pragma unroll
        for (int g = 0; g < 3; ++g) {
            uint4 e4 = *(const uint4*)(ewp + g * 4);         // uniform broadcast
            #pragma unroll
            for (int t = 0; t < 4; ++t) {
                int u = g * 4 + t;
                uint e0 = (u < cnt) ? ((const uint*)&e4)[t] : 0xffffffffu;
                uint v = *(const uint*)(wbuf + u * 256 + lane4);
                uint p;
                asm("v_pk_mul_f16 %0, %1, %2 op_sel:[0,1] op_sel_hi:[1,1]"
                    : "=v"(p) : "v"(v), "v"(e0));            // both halves * hi16(entry)
                asm("v_pk_max_f16 %0, %0, %1" : "+v"(mm[u & 3]) : "v"(p));
            }
        }
        // second half: rows 12..23 after vmcnt(0)
        asm volatile("s_waitcnt vmcnt(0)" ::: "memory");
        #pragma unroll
        for (int g = 3; g < SLOTS / 4; ++g) {
            uint4 e4 = *(const uint4*)(ewp + g * 4);
            #pragma unroll
            for (int t = 0; t < 4; ++t) {
                int u = g * 4 + t;
                uint e0 = (u < cnt) ? ((const uint*)&e4)[t] : 0xffffffffu;
                uint v = *(const uint*)(wbuf + u * 256 + lane4);
                uint p;
                asm("v_pk_mul_f16 %0, %1, %2 op_sel:[0,1] op_sel_hi:[1,1]"
                    : "=v"(p) : "v"(v), "v"(e0));
                asm("v_pk_max_f16 %0, %0, %1" : "+v"(mm[u & 3]) : "v"(p));
            }
        }
        // remainder edges 24..cnt (P(deg>24) ~ 2.6%): serial, direct from global
        for (int i = SLOTS; i < cnt; ++i) {
            uint e0 = ewp[i];
            uint v  = *(const uint*)(xhb + ((e0 & 0xffffu) << 8) + lane4);
            uint p;
            asm("v_pk_mul_f16 %0, %1, %2 op_sel:[0,1] op_sel_hi:[1,1]"
                : "=v"(p) : "v"(v), "v"(e0));
            asm("v_pk_max_f16 %0, %0, %1" : "+v"(mm[0]) : "v"(p));
        }

        // reduce 4 -> 1
        asm("v_pk_max_f16 %0, %0, %1" : "+v"(mm[0]) : "v"(mm[1]));
        asm("v_pk_max_f16 %0, %0, %1" : "+v"(mm[2]) : "v"(mm[3]));
        asm("v_pk_max_f16 %0, %0, %1" : "+v"(mm[0]) : "v"(mm[2]));
        float mx = h2f((ushort)(mm[0] & 0xffffu));
        float my = h2f((ushort)(mm[0] >> 16));

        // overflow edges (exactness insurance; statistically never taken)
        if (deg[j] > CAP) {
            int novf = ws[OVF_CNT_OFF] + 1;
            if (novf > OVF_CAP) novf = OVF_CAP;
            for (int o = 0; o < novf; ++o) {
                if (ws[OVF_OFF + 2 * o] == n) {
                    uint e0 = (uint)ws[OVF_OFF + 2 * o + 1];
                    uint v  = xh[(e0 & 0xffffu) * 64 + lane];
                    float w = h2f((ushort)(e0 >> 16));
                    mx = fmaxf(mx, h2f((ushort)(v & 0xffffu)) * w);
                    my = fmaxf(my, h2f((ushort)(v >> 16)) * w);
                }
            }
        }
        if (deg[j] == 0) { mx = 0.f; my = 0.f; }             // isolated node -> 0

        // self term from prefetched row
        float t0 = eps1 * h2f((ushort)(xv[j] & 0xffffu)) + mx;
        float t1 = eps1 * h2f((ushort)(xv[j] >> 16)) + my;
        tl[nl * (HSTRIDE / 2) + lane] = (uint)f2h(t0) | ((uint)f2h(t1) << 16);
    }
    __syncthreads();

    // A frags from LDS t tile
    half8 a[4];
    {
        const ushort* arow = (const ushort*)tl + m * HSTRIDE + quad * 8;
        #pragma unroll
        for (int kb = 0; kb < 4; ++kb) a[kb] = *(const half8*)(arow + kb * 32);
    }

    // GEMM1 + bias + LeakyReLU -> hl (overlaid on gather buffer)
    #pragma unroll
    for (int t = 0; t < 2; ++t) {
        int ct = wave * 2 + t;
        float4v c = {0.f, 0.f, 0.f, 0.f};
        const ushort* brow = w1h + (size_t)(ct * 16 + m) * 128 + quad * 8;
        #pragma unroll
        for (int kb = 0; kb < 4; ++kb)
            c = __builtin_amdgcn_mfma_f32_16x16x32_f16(a[kb], *(const half8*)(brow + kb * 32), c, 0, 0, 0);
        float bias = f32 ? ((const float*)b1raw)[ct * 16 + m] : b2f(b1raw[ct * 16 + m]);
        #pragma unroll
        for (int r = 0; r < 4; ++r) {
            float v = c[r] + bias;
            v = (v >= 0.f) ? v : 0.01f * v;
            hl[(quad * 4 + r) * HSTRIDE + ct * 16 + m] = f2h(v);
        }
    }
    __syncthreads();

    // A frags for GEMM2 from hl
    half8 ah[4];
    {
        const ushort* hrow = hl + m * HSTRIDE + quad * 8;
        #pragma unroll
        for (int kb = 0; kb < 4; ++kb) ah[kb] = *(const half8*)(hrow + kb * 32);
    }

    // GEMM2 + bias -> out
    #pragma unroll
    for (int t = 0; t < 2; ++t) {
        int ct = wave * 2 + t;
        float4v c = {0.f, 0.f, 0.f, 0.f};
        const ushort* brow = w2h + (size_t)(ct * 16 + m) * 128 + quad * 8;
        #pragma unroll
        for (int kb = 0; kb < 4; ++kb)
            c = __builtin_amdgcn_mfma_f32_16x16x32_f16(ah[kb], *(const half8*)(brow + kb * 32), c, 0, 0, 0);
        float bias = f32 ? ((const float*)b2raw)[ct * 16 + m] : b2f(b2raw[ct * 16 + m]);
        #pragma unroll
        for (int r = 0; r < 4; ++r) {
            float v = c[r] + bias;
            size_t o = (size_t)(node0 + quad * 4 + r) * 128 + ct * 16 + m;
            if (f32) ((float*)outraw)[o] = v;
            else     outraw[o] = f2b(v);
        }
    }
}

// ================= host =================
extern "C" void kernel_launch(void* const* d_in, const int* in_sizes, int n_in,
                              void* d_out, int out_size, void* d_ws, size_t ws_size,
                              hipStream_t stream) {
    const uint16_t* x    = (const uint16_t*)d_in[0];
    const int*      eidx = (const int*)     d_in[1];
    const uint16_t* ew   = (const uint16_t*)d_in[2];
    const uint16_t* w1   = (const uint16_t*)d_in[3];
    const uint16_t* b1   = (const uint16_t*)d_in[4];
    const uint16_t* w2   = (const uint16_t*)d_in[5];
    const uint16_t* b2   = (const uint16_t*)d_in[6];
    const uint16_t* eps  = (const uint16_t*)d_in[7];
    uint16_t*       out  = (uint16_t*)d_out;
    int* ws = (int*)d_ws;

    // Only counters (+ overflow counter) need init (-1). Buckets are left
    // uninitialized: the gather's entry-level tail-mask handles garbage.
    hipMemsetAsync((char*)d_ws + (size_t)CNT_OFF * 4, 0xFF,
                   (size_t)(NN + 1) * 4, stream);
    prep_fill_kernel<<<FILL_BLKS + PX_BLKS + PW_BLKS, 256, 0, stream>>>(
        x, eidx, ew, w1, w2, ws);
    gmlp_kernel<<<NN / 16, 256, 0, stream>>>(x, eidx, b1, b2, eps, ws, out);
}

// Round 7
// 198.055 us; speedup vs baseline: 1.0405x; 1.0405x over previous
//
#include <hip/hip_runtime.h>
#include <stdint.h>

#define NN 50000
#define NE 800000
#define D  128
#define CAP 64                            // compacted entries staged per node (deg>64: P~1e-19)
#define SCAP 10                           // per-XCD sub-bucket cap (deg/XCD ~ Poisson(2); P(>10)~8e-6)
#define NXCD 8
#define OVF_CAP 65536

// ---------------- ws layout (int offsets) ----------------
// Per-XCD counters init to -1 via 0xFF memset (slot = atomicAdd()+1), filled
// with XCD-LOCAL (workgroup-scope) atomics: each XCD's CUs are the only
// writers of their region, so the L2-local RMW is atomic; cross-kernel
// visibility via the dispatch-boundary L2 writeback (same guarantee the
// plain bucket stores already rely on). Sub-buckets UNINITIALIZED.
#define CNT8_OFF    64                    // 8*NN per-XCD counters
#define OVF_CNT_OFF (CNT8_OFF + NXCD * NN)          // 400064
#define OVF_OFF     (OVF_CNT_OFF + 4)               // 400068: OVF_CAP pairs (dst, entry)
#define BKT8_OFF    531200                // 8*NN*SCAP entries: (w_fp16<<16)|src
#define XH_OFF      (BKT8_OFF + NXCD * NN * SCAP)   // 4531200: x fp16 pairs, NN+1 rows (row NN = pad)
#define WH_OFF      (XH_OFF + (NN + 1) * (D / 2))   // 7731264: w1+w2 fp16
// high-water: 7,747,648 ints = 31.0 MB (< 32.4 MB proven available)

#define HSTRIDE 136                       // LDS row stride in ushorts (272 B, 2-way banks = free)
#define SLOTS   24                        // staged row-gathers per node (fixed, unrolled)
#define WLDS    (SLOTS * 256 + 1024)      // per-wave LDS: 24 value rows + 4x64-entry compact lists

// fused prep+fill block ranges
#define FILL_BLKS 3125                    // NE/256 (1 edge/thread)
#define PX_BLKS   6250                    // NN*D/1024
#define PW_BLKS   32

typedef _Float16 half8 __attribute__((ext_vector_type(8)));
typedef __attribute__((ext_vector_type(4))) float float4v;

// ---------------- dtype helpers ----------------
__device__ __forceinline__ float b2f(uint16_t u) {
    union { uint32_t u; float f; } v; v.u = ((uint32_t)u) << 16; return v.f;
}
__device__ __forceinline__ uint16_t f2b(float f) {
    union { float f; uint32_t u; } v; v.f = f;
    uint32_t r = v.u + 0x7fffu + ((v.u >> 16) & 1u);   // RNE
    return (uint16_t)(r >> 16);
}
__device__ __forceinline__ ushort f2h(float f) {
    union { _Float16 h; ushort u; } v; v.h = (_Float16)f; return v.u;   // v_cvt_f16_f32 (RNE)
}
__device__ __forceinline__ float h2f(ushort u) {
    union { ushort u; _Float16 h; } v; v.u = u; return (float)v.h;
}

// async global->LDS, 16 B/lane: LDS dest = uniform base + lane*16 (1 KB =
// four 256 B rows); global src per-lane. Counts in vmcnt.
__device__ __forceinline__ void gload_lds16(const void* g, void* l) {
    __builtin_amdgcn_global_load_lds(
        (const __attribute__((address_space(1))) void*)g,
        (__attribute__((address_space(3))) void*)l, 16, 0, 0);
}

// ---------------- per-block inline dtype probe (load-bearing; rounds 2-9) ----------------
__device__ __forceinline__ void block_probe(const uint16_t* __restrict__ xraw,
                                            const int* __restrict__ eraw,
                                            int* sflags) {
    int t = threadIdx.x;
    if (t < 64) {                                   // wave 0 only
        float v0 = b2f(xraw[2 * t]);
        float v1 = b2f(xraw[2 * t + 1]);
        int bad = (!(v0 > -1e4f && v0 < 1e4f)) || (!(v1 > -1e4f && v1 < 1e4f));
        unsigned long long bm = __ballot(bad);
        int nz = (t < 32) ? (eraw[2 * t + 1] != 0) : 0;
        unsigned long long im = __ballot(nz);
        if (t == 0) { sflags[0] = bm ? 1 : 0; sflags[1] = im ? 0 : 1; }
    }
    __syncthreads();
}

// ---------------- fused fill + prep_x + prep_w ----------------
__global__ __launch_bounds__(256) void prep_fill_kernel(
    const uint16_t* __restrict__ xraw,
    const int*      __restrict__ eraw,
    const uint16_t* __restrict__ ewraw,
    const uint16_t* __restrict__ w1raw,
    const uint16_t* __restrict__ w2raw,
    int* __restrict__ ws)
{
    __shared__ int sflags[2];
    block_probe(xraw, eraw, sflags);
    const int f32 = sflags[0], i64 = sflags[1];

    int bid = blockIdx.x;
    if (bid < FILL_BLKS) {
        // ---- edge fill: XCD-local counter atomic + sub-bucket write ----
        uint xcd;
        asm volatile("s_getreg_b32 %0, hwreg(HW_REG_XCC_ID)" : "=s"(xcd));
        xcd &= (NXCD - 1);

        int e = bid * 256 + threadIdx.x;
        int src, dst;
        if (i64) {
            const long long* e64 = (const long long*)eraw;
            src = (int)e64[e];
            dst = (int)e64[NE + e];
        } else {
            src = eraw[e];
            dst = eraw[NE + e];
        }
        if ((unsigned)src >= NN || (unsigned)dst >= NN) return;
        uint w = f32 ? (uint)f2h(((const float*)ewraw)[e]) : (uint)f2h(b2f(ewraw[e]));
        uint entry = (w << 16) | (uint)src;
        // L2-local RMW: only this XCD's CUs touch cnt8[xcd][*]
        int slot = __hip_atomic_fetch_add(ws + CNT8_OFF + (size_t)xcd * NN + dst, 1,
                                          __ATOMIC_RELAXED, __HIP_MEMORY_SCOPE_WORKGROUP) + 1;
        if (slot < SCAP) {
            ((uint*)(ws + BKT8_OFF))[((size_t)xcd * NN + dst) * SCAP + slot] = entry;
        } else {
            int o = atomicAdd(ws + OVF_CNT_OFF, 1) + 1;      // rare: device scope fine
            if (o < OVF_CAP) {
                ws[OVF_OFF + 2 * o]     = dst;
                ws[OVF_OFF + 2 * o + 1] = (int)entry;
            }
        }
    } else if (bid < FILL_BLKS + PX_BLKS) {
        // ---- x -> fp16 table ----
        int i4 = ((bid - FILL_BLKS) * 256 + threadIdx.x) * 4;   // covers NN*D exactly
        ushort* dst = (ushort*)(ws + XH_OFF);
        if (f32) {
            float4 v = *(const float4*)((const float*)xraw + i4);
            ushort4 o; o.x = f2h(v.x); o.y = f2h(v.y); o.z = f2h(v.z); o.w = f2h(v.w);
            *(ushort4*)(dst + i4) = o;
        } else {
            ushort4 v = *(const ushort4*)(xraw + i4);
            ushort4 o; o.x = f2h(b2f(v.x)); o.y = f2h(b2f(v.y));
            o.z = f2h(b2f(v.z)); o.w = f2h(b2f(v.w));
            *(ushort4*)(dst + i4) = o;
        }
    } else {
        // ---- w1,w2 -> fp16 table ----
        int i4 = ((bid - FILL_BLKS - PX_BLKS) * 256 + threadIdx.x) * 4; // 0..32764
        const uint16_t* src = (i4 < 16384) ? w1raw : w2raw;
        int off = i4 & 16383;
        ushort* dst = (ushort*)(ws + WH_OFF);
        if (f32) {
            float4 v = *(const float4*)((const float*)src + off);
            ushort4 o; o.x = f2h(v.x); o.y = f2h(v.y); o.z = f2h(v.z); o.w = f2h(v.w);
            *(ushort4*)(dst + i4) = o;
        } else {
            ushort4 v = *(const ushort4*)(src + off);
            ushort4 o; o.x = f2h(b2f(v.x)); o.y = f2h(b2f(v.y));
            o.z = f2h(b2f(v.z)); o.w = f2h(b2f(v.w));
            *(ushort4*)(dst + i4) = o;
        }
    }
}

// ---------------- fused gather-max + MFMA MLP ----------------
// 16 nodes/block, 4 waves. Up-front in-wave COMPACTION merges the 8 XCD
// sub-buckets per node into a 64-entry LDS list (8-lane count load ->
// shfl prefix scan -> one 64-lane entry gather -> ds_write). The proven
// 24-slot 16B-DMA staging/consume loop then runs unchanged against the
// compact list. Tails masked to 0xFFFFFFFF (NaN weight, pad row NN).
__global__ __launch_bounds__(256, 4) void gmlp_kernel(
    const uint16_t* __restrict__ xraw,
    const int*      __restrict__ eraw,
    const uint16_t* __restrict__ b1raw,
    const uint16_t* __restrict__ b2raw,
    const uint16_t* __restrict__ epsraw,
    const int* __restrict__ ws,
    uint16_t* __restrict__ outraw)
{
    __shared__ char smem[4][WLDS];              // per-wave: [0,6144) value rows, [6144,7168) compact lists
    __shared__ uint tl[16 * (HSTRIDE / 2)];     // t tile, 68 uints/row
    __shared__ int  sflags[2];
    ushort* hl = (ushort*)&smem[0][0];          // hidden tile overlay (post-sync)

    const int tid  = threadIdx.x;
    const int wave = tid >> 6;
    const int lane = tid & 63;
    const int m    = lane & 15;
    const int quad = lane >> 4;
    const int node0 = blockIdx.x * 16;

    const ushort* w1h = (const ushort*)(ws + WH_OFF);
    const ushort* w2h = w1h + 16384;
    const uint*   xh  = (const uint*)(ws + XH_OFF);
    const char*   xhb = (const char*)xh;
    const uint*   bkt8 = (const uint*)(ws + BKT8_OFF);
    const uint    lane4 = (uint)lane * 4;
    const uint    sub16 = (uint)(lane & 15) * 16;
    char*         wbuf  = smem[wave];
    uint*         ebw   = (uint*)(wbuf + SLOTS * 256);   // 4 x 64-entry compact lists

    // ---- compaction: 8 sub-buckets -> ebuf[j][64] ----
    int total[4], ecnt[4]; bool ovfl[4];
    #pragma unroll
    for (int j = 0; j < 4; ++j) {
        int n = node0 + wave * 4 + j;
        int raw = 0;
        if (lane < 8) raw = ws[CNT8_OFF + lane * NN + n] + 1;    // deg on XCD 'lane'
        int ck = (raw < SCAP) ? raw : SCAP;
        int inc = ck;
        #pragma unroll
        for (int d = 1; d < 8; d <<= 1) {
            int v = __shfl_up(inc, d);
            if (lane >= d) inc += v;
        }
        int tot = __shfl(inc, 7);
        total[j] = tot;
        ecnt[j]  = (tot < CAP) ? tot : CAP;
        ovfl[j]  = (__ballot(lane < 8 && raw > SCAP) != 0ull);
        int kk = 0, off = 0, prev = 0;
        #pragma unroll
        for (int k2 = 0; k2 < 8; ++k2) {
            int ik = __shfl(inc, k2);
            if (lane >= prev && lane < ik) { kk = k2; off = lane - prev; }
            prev = ik;
        }
        uint e = 0xffffffffu;
        if (lane < ecnt[j]) e = bkt8[((size_t)kk * NN + n) * SCAP + off];
        ebw[j * 64 + lane] = e;
    }

    // self-row prefetch
    uint xv[4];
    #pragma unroll
    for (int j = 0; j < 4; ++j)
        xv[j] = xh[(size_t)(node0 + wave * 4 + j) * 64 + lane];

    block_probe(xraw, eraw, sflags);
    const int f32 = sflags[0];
    const float eps1 = 1.0f + (f32 ? ((const float*)epsraw)[0] : b2f(epsraw[0]));

    #pragma unroll
    for (int j = 0; j < 4; ++j) {
        int nl = wave * 4 + j;
        int n  = node0 + nl;
        int cnt = ecnt[j];
        const uint* ewp = ebw + j * 64;

        // prior node's ds_reads / this node's list writes must be done
        asm volatile("s_waitcnt lgkmcnt(0)" ::: "memory");

        // issue: 6 grouped stages; lane group (lane>>4) covers row 4g+grp
        #pragma unroll
        for (int g = 0; g < SLOTS / 4; ++g) {
            uint slot = (uint)(g * 4) + (uint)(lane >> 4);
            uint e0 = ewp[slot];                             // broadcast ds_read
            e0 = (slot < (uint)cnt) ? e0 : 0xffffffffu;
            uint row = e0 & 0xffffu;
            row = (row < NN) ? row : NN;                     // pad -> dedicated row NN
            gload_lds16(xhb + ((size_t)row << 8) + sub16, wbuf + g * 1024);
        }

        uint mm[4] = {~0u, ~0u, ~0u, ~0u};                   // packed fp16 NaN,NaN

        // first half: rows 0..11 after vmcnt(3)
        asm volatile("s_waitcnt vmcnt(3)" ::: "memory");
        #pragma unroll
        for (int g = 0; g < 3; ++g) {
            uint4 e4 = *(const uint4*)(ewp + g * 4);
            #pragma unroll
            for (int t = 0; t < 4; ++t) {
                int u = g * 4 + t;
                uint e0 = (u < cnt) ? ((const uint*)&e4)[t] : 0xffffffffu;
                uint v = *(const uint*)(wbuf + u * 256 + lane4);
                uint p;
                asm("v_pk_mul_f16 %0, %1, %2 op_sel:[0,1] op_sel_hi:[1,1]"
                    : "=v"(p) : "v"(v), "v"(e0));
                asm("v_pk_max_f16 %0, %0, %1" : "+v"(mm[u & 3]) : "v"(p));
            }
        }
        // second half: rows 12..23 after vmcnt(0)
        asm volatile("s_waitcnt vmcnt(0)" ::: "memory");
        #pragma unroll
        for (int g = 3; g < SLOTS / 4; ++g) {
            uint4 e4 = *(const uint4*)(ewp + g * 4);
            #pragma unroll
            for (int t = 0; t < 4; ++t) {
                int u = g * 4 + t;
                uint e0 = (u < cnt) ? ((const uint*)&e4)[t] : 0xffffffffu;
                uint v = *(const uint*)(wbuf + u * 256 + lane4);
                uint p;
                asm("v_pk_mul_f16 %0, %1, %2 op_sel:[0,1] op_sel_hi:[1,1]"
                    : "=v"(p) : "v"(v), "v"(e0));
                asm("v_pk_max_f16 %0, %0, %1" : "+v"(mm[u & 3]) : "v"(p));
            }
        }
        // remainder entries 24..cnt from compact list (P(deg>24) ~ 2.6%)
        for (int i = SLOTS; i < cnt; ++i) {
            uint e0 = ewp[i];
            uint v  = *(const uint*)(xhb + ((size_t)(e0 & 0xffffu) << 8) + lane4);
            uint p;
            asm("v_pk_mul_f16 %0, %1, %2 op_sel:[0,1] op_sel_hi:[1,1]"
                : "=v"(p) : "v"(v), "v"(e0));
            asm("v_pk_max_f16 %0, %0, %1" : "+v"(mm[0]) : "v"(p));
        }
        // entries beyond 64 (deg > 64; P ~ 1e-19): walk sub-buckets directly
        if (total[j] > CAP) {
            int idx = 0;
            for (int k2 = 0; k2 < 8; ++k2) {
                int raw2 = ws[CNT8_OFF + k2 * NN + n] + 1;
                int c2 = (raw2 < SCAP) ? raw2 : SCAP;
                for (int o2 = 0; o2 < c2; ++o2) {
                    if (idx >= CAP) {
                        uint e0 = bkt8[((size_t)k2 * NN + n) * SCAP + o2];
                        uint v  = *(const uint*)(xhb + ((size_t)(e0 & 0xffffu) << 8) + lane4);
                        uint p;
                        asm("v_pk_mul_f16 %0, %1, %2 op_sel:[0,1] op_sel_hi:[1,1]"
                            : "=v"(p) : "v"(v), "v"(e0));
                        asm("v_pk_max_f16 %0, %0, %1" : "+v"(mm[0]) : "v"(p));
                    }
                    ++idx;
                }
            }
        }

        // reduce 4 -> 1
        asm("v_pk_max_f16 %0, %0, %1" : "+v"(mm[0]) : "v"(mm[1]));
        asm("v_pk_max_f16 %0, %0, %1" : "+v"(mm[2]) : "v"(mm[3]));
        asm("v_pk_max_f16 %0, %0, %1" : "+v"(mm[0]) : "v"(mm[2]));
        float mx = h2f((ushort)(mm[0] & 0xffffu));
        float my = h2f((ushort)(mm[0] >> 16));

        // sub-bucket overflow entries (rare: ~3 expected events per run)
        if (ovfl[j]) {
            int novf = ws[OVF_CNT_OFF] + 1;
            if (novf > OVF_CAP) novf = OVF_CAP;
            for (int o = 0; o < novf; ++o) {
                if (ws[OVF_OFF + 2 * o] == n) {
                    uint e0 = (uint)ws[OVF_OFF + 2 * o + 1];
                    uint v  = xh[(size_t)(e0 & 0xffffu) * 64 + lane];
                    float w = h2f((ushort)(e0 >> 16));
                    mx = fmaxf(mx, h2f((ushort)(v & 0xffffu)) * w);
                    my = fmaxf(my, h2f((ushort)(v >> 16)) * w);
                }
            }
        }
        if (total[j] == 0) { mx = 0.f; my = 0.f; }           // isolated node -> 0

        // self term from prefetched row
        float t0 = eps1 * h2f((ushort)(xv[j] & 0xffffu)) + mx;
        float t1 = eps1 * h2f((ushort)(xv[j] >> 16)) + my;
        tl[nl * (HSTRIDE / 2) + lane] = (uint)f2h(t0) | ((uint)f2h(t1) << 16);
    }
    __syncthreads();

    // A frags from LDS t tile
    half8 a[4];
    {
        const ushort* arow = (const ushort*)tl + m * HSTRIDE + quad * 8;
        #pragma unroll
        for (int kb = 0; kb < 4; ++kb) a[kb] = *(const half8*)(arow + kb * 32);
    }

    // GEMM1 + bias + LeakyReLU -> hl (overlaid on gather buffer)
    #pragma unroll
    for (int t = 0; t < 2; ++t) {
        int ct = wave * 2 + t;
        float4v c = {0.f, 0.f, 0.f, 0.f};
        const ushort* brow = w1h + (size_t)(ct * 16 + m) * 128 + quad * 8;
        #pragma unroll
        for (int kb = 0; kb < 4; ++kb)
            c = __builtin_amdgcn_mfma_f32_16x16x32_f16(a[kb], *(const half8*)(brow + kb * 32), c, 0, 0, 0);
        float bias = f32 ? ((const float*)b1raw)[ct * 16 + m] : b2f(b1raw[ct * 16 + m]);
        #pragma unroll
        for (int r = 0; r < 4; ++r) {
            float v = c[r] + bias;
            v = (v >= 0.f) ? v : 0.01f * v;
            hl[(quad * 4 + r) * HSTRIDE + ct * 16 + m] = f2h(v);
        }
    }
    __syncthreads();

    // A frags for GEMM2 from hl
    half8 ah[4];
    {
        const ushort* hrow = hl + m * HSTRIDE + quad * 8;
        #pragma unroll
        for (int kb = 0; kb < 4; ++kb) ah[kb] = *(const half8*)(hrow + kb * 32);
    }

    // GEMM2 + bias -> out
    #pragma unroll
    for (int t = 0; t < 2; ++t) {
        int ct = wave * 2 + t;
        float4v c = {0.f, 0.f, 0.f, 0.f};
        const ushort* brow = w2h + (size_t)(ct * 16 + m) * 128 + quad * 8;
        #pragma unroll
        for (int kb = 0; kb < 4; ++kb)
            c = __builtin_amdgcn_mfma_f32_16x16x32_f16(ah[kb], *(const half8*)(brow + kb * 32), c, 0, 0, 0);
        float bias = f32 ? ((const float*)b2raw)[ct * 16 + m] : b2f(b2raw[ct * 16 + m]);
        #pragma unroll
        for (int r = 0; r < 4; ++r) {
            float v = c[r] + bias;
            size_t o = (size_t)(node0 + quad * 4 + r) * 128 + ct * 16 + m;
            if (f32) ((float*)outraw)[o] = v;
            else     outraw[o] = f2b(v);
        }
    }
}

// ================= host =================
extern "C" void kernel_launch(void* const* d_in, const int* in_sizes, int n_in,
                              void* d_out, int out_size, void* d_ws, size_t ws_size,
                              hipStream_t stream) {
    const uint16_t* x    = (const uint16_t*)d_in[0];
    const int*      eidx = (const int*)     d_in[1];
    const uint16_t* ew   = (const uint16_t*)d_in[2];
    const uint16_t* w1   = (const uint16_t*)d_in[3];
    const uint16_t* b1   = (const uint16_t*)d_in[4];
    const uint16_t* w2   = (const uint16_t*)d_in[5];
    const uint16_t* b2   = (const uint16_t*)d_in[6];
    const uint16_t* eps  = (const uint16_t*)d_in[7];
    uint16_t*       out  = (uint16_t*)d_out;
    int* ws = (int*)d_ws;

    // init 8 per-XCD counter arrays (+ overflow counter) to -1
    hipMemsetAsync((char*)d_ws + (size_t)CNT8_OFF * 4, 0xFF,
                   ((size_t)NXCD * NN + 1) * 4, stream);
    prep_fill_kernel<<<FILL_BLKS + PX_BLKS + PW_BLKS, 256, 0, stream>>>(
        x, eidx, ew, w1, w2, ws);
    gmlp_kernel<<<NN / 16, 256, 0, stream>>>(x, eidx, b1, b2, eps, ws, out);
}

// Round 8
// 196.663 us; speedup vs baseline: 1.0478x; 1.0071x over previous
//
#include <hip/hip_runtime.h>
#include <stdint.h>

#define NN 50000
#define NE 800000
#define D  128
#define CAP 64                            // compacted entries staged per node (8/XCD x 8)
#define SCAP 10                           // per-XCD sub-bucket cap (deg/XCD ~ Poisson(2))
#define NXCD 8
#define OVF_CAP 65536

// ---------------- ws layout (int offsets) ----------------
// Per-XCD counters init to -1 via 0xFF memset (slot = atomicAdd()+1), filled
// with XCD-LOCAL (workgroup-scope) atomics: each XCD's CUs are the only
// writers of their region, so the L2-local RMW is atomic; cross-kernel
// visibility via the dispatch-boundary L2 writeback. Sub-buckets UNINIT.
#define CNT8_OFF    64                    // 8*NN per-XCD counters
#define OVF_CNT_OFF (CNT8_OFF + NXCD * NN)          // 400064
#define OVF_OFF     (OVF_CNT_OFF + 4)               // 400068: OVF_CAP pairs (dst, entry)
#define BKT8_OFF    531200                // 8*NN*SCAP entries: (w_fp16<<16)|src
#define XH_OFF      (BKT8_OFF + NXCD * NN * SCAP)   // 4531200: x fp16 pairs, NN+1 rows (row NN = pad)
#define WH_OFF      (XH_OFF + (NN + 1) * (D / 2))   // 7731264: w1+w2 fp16
// high-water: 7,747,648 ints = 31.0 MB (< 32.4 MB proven available)

#define HSTRIDE 136                       // LDS row stride in ushorts (272 B, 2-way banks = free)
#define SLOTS   24                        // staged row-gathers per node (fixed, unrolled)
#define WLDS    (SLOTS * 256 + 1024)      // per-wave LDS: 24 value rows + 4x64-entry compact lists

// fused prep+fill block ranges
#define FILL_BLKS 3125                    // NE/256 (1 edge/thread)
#define PX_BLKS   6250                    // NN*D/1024
#define PW_BLKS   32

typedef _Float16 half8 __attribute__((ext_vector_type(8)));
typedef __attribute__((ext_vector_type(4))) float float4v;

// ---------------- dtype helpers ----------------
__device__ __forceinline__ float b2f(uint16_t u) {
    union { uint32_t u; float f; } v; v.u = ((uint32_t)u) << 16; return v.f;
}
__device__ __forceinline__ uint16_t f2b(float f) {
    union { float f; uint32_t u; } v; v.f = f;
    uint32_t r = v.u + 0x7fffu + ((v.u >> 16) & 1u);   // RNE
    return (uint16_t)(r >> 16);
}
__device__ __forceinline__ ushort f2h(float f) {
    union { _Float16 h; ushort u; } v; v.h = (_Float16)f; return v.u;   // v_cvt_f16_f32 (RNE)
}
__device__ __forceinline__ float h2f(ushort u) {
    union { ushort u; _Float16 h; } v; v.u = u; return (float)v.h;
}

// async global->LDS, 16 B/lane: LDS dest = uniform base + lane*16 (1 KB =
// four 256 B rows); global src per-lane. Counts in vmcnt.
__device__ __forceinline__ void gload_lds16(const void* g, void* l) {
    __builtin_amdgcn_global_load_lds(
        (const __attribute__((address_space(1))) void*)g,
        (__attribute__((address_space(3))) void*)l, 16, 0, 0);
}

__device__ __forceinline__ uint mbcnt64(unsigned long long m) {
    return __builtin_amdgcn_mbcnt_hi((uint)(m >> 32),
           __builtin_amdgcn_mbcnt_lo((uint)m, 0u));
}

// ---------------- per-block inline dtype probe (load-bearing; rounds 2-9) ----------------
__device__ __forceinline__ void block_probe(const uint16_t* __restrict__ xraw,
                                            const int* __restrict__ eraw,
                                            int* sflags) {
    int t = threadIdx.x;
    if (t < 64) {                                   // wave 0 only
        float v0 = b2f(xraw[2 * t]);
        float v1 = b2f(xraw[2 * t + 1]);
        int bad = (!(v0 > -1e4f && v0 < 1e4f)) || (!(v1 > -1e4f && v1 < 1e4f));
        unsigned long long bm = __ballot(bad);
        int nz = (t < 32) ? (eraw[2 * t + 1] != 0) : 0;
        unsigned long long im = __ballot(nz);
        if (t == 0) { sflags[0] = bm ? 1 : 0; sflags[1] = im ? 0 : 1; }
    }
    __syncthreads();
}

// ---------------- fused fill + prep_x + prep_w ----------------
__global__ __launch_bounds__(256) void prep_fill_kernel(
    const uint16_t* __restrict__ xraw,
    const int*      __restrict__ eraw,
    const uint16_t* __restrict__ ewraw,
    const uint16_t* __restrict__ w1raw,
    const uint16_t* __restrict__ w2raw,
    int* __restrict__ ws)
{
    __shared__ int sflags[2];
    block_probe(xraw, eraw, sflags);
    const int f32 = sflags[0], i64 = sflags[1];

    int bid = blockIdx.x;
    if (bid < FILL_BLKS) {
        // ---- edge fill: XCD-local counter atomic + sub-bucket write ----
        uint xcd;
        asm volatile("s_getreg_b32 %0, hwreg(HW_REG_XCC_ID)" : "=s"(xcd));
        xcd &= (NXCD - 1);

        int e = bid * 256 + threadIdx.x;
        int src, dst;
        if (i64) {
            const long long* e64 = (const long long*)eraw;
            src = (int)e64[e];
            dst = (int)e64[NE + e];
        } else {
            src = eraw[e];
            dst = eraw[NE + e];
        }
        if ((unsigned)src >= NN || (unsigned)dst >= NN) return;
        uint w = f32 ? (uint)f2h(((const float*)ewraw)[e]) : (uint)f2h(b2f(ewraw[e]));
        uint entry = (w << 16) | (uint)src;
        // L2-local RMW: only this XCD's CUs touch cnt8[xcd][*]
        int slot = __hip_atomic_fetch_add(ws + CNT8_OFF + (size_t)xcd * NN + dst, 1,
                                          __ATOMIC_RELAXED, __HIP_MEMORY_SCOPE_WORKGROUP) + 1;
        if (slot < SCAP) {
            ((uint*)(ws + BKT8_OFF))[((size_t)xcd * NN + dst) * SCAP + slot] = entry;
        } else {
            int o = atomicAdd(ws + OVF_CNT_OFF, 1) + 1;      // rare: device scope fine
            if (o < OVF_CAP) {
                ws[OVF_OFF + 2 * o]     = dst;
                ws[OVF_OFF + 2 * o + 1] = (int)entry;
            }
        }
    } else if (bid < FILL_BLKS + PX_BLKS) {
        // ---- x -> fp16 table ----
        int i4 = ((bid - FILL_BLKS) * 256 + threadIdx.x) * 4;   // covers NN*D exactly
        ushort* dst = (ushort*)(ws + XH_OFF);
        if (f32) {
            float4 v = *(const float4*)((const float*)xraw + i4);
            ushort4 o; o.x = f2h(v.x); o.y = f2h(v.y); o.z = f2h(v.z); o.w = f2h(v.w);
            *(ushort4*)(dst + i4) = o;
        } else {
            ushort4 v = *(const ushort4*)(xraw + i4);
            ushort4 o; o.x = f2h(b2f(v.x)); o.y = f2h(b2f(v.y));
            o.z = f2h(b2f(v.z)); o.w = f2h(b2f(v.w));
            *(ushort4*)(dst + i4) = o;
        }
    } else {
        // ---- w1,w2 -> fp16 table ----
        int i4 = ((bid - FILL_BLKS - PX_BLKS) * 256 + threadIdx.x) * 4; // 0..32764
        const uint16_t* src = (i4 < 16384) ? w1raw : w2raw;
        int off = i4 & 16383;
        ushort* dst = (ushort*)(ws + WH_OFF);
        if (f32) {
            float4 v = *(const float4*)((const float*)src + off);
            ushort4 o; o.x = f2h(v.x); o.y = f2h(v.y); o.z = f2h(v.z); o.w = f2h(v.w);
            *(ushort4*)(dst + i4) = o;
        } else {
            ushort4 v = *(const ushort4*)(src + off);
            ushort4 o; o.x = f2h(b2f(v.x)); o.y = f2h(b2f(v.y));
            o.z = f2h(b2f(v.z)); o.w = f2h(b2f(v.w));
            *(ushort4*)(dst + i4) = o;
        }
    }
}

// ---------------- fused gather-max + MFMA MLP ----------------
// 16 nodes/block, 4 waves. Cheap wave-native compaction (the R7 version's
// scan+search was ~9 us): lane L covers sub-entry (xcd=L>>3, idx=L&7);
// valid = idx < min(count,8); dense rank via ballot+mbcnt; invalid lanes
// take the complementary high slots (bijective); ONE ds_permute pushes
// entries dense (invalid lanes carry 0xFFFFFFFF = NaN entries). The proven
// 24-slot 16B-DMA staging/consume loop runs unchanged on the dense list.
// Sub-entries with idx>=8 (P~1e-4/sub-bucket) are consumed directly in a
// rare uniform branch; >=SCAP entries come from the device-scope ovf list.
__global__ __launch_bounds__(256, 4) void gmlp_kernel(
    const uint16_t* __restrict__ xraw,
    const int*      __restrict__ eraw,
    const uint16_t* __restrict__ b1raw,
    const uint16_t* __restrict__ b2raw,
    const uint16_t* __restrict__ epsraw,
    const int* __restrict__ ws,
    uint16_t* __restrict__ outraw)
{
    __shared__ char smem[4][WLDS];              // per-wave: [0,6144) value rows, [6144,7168) compact lists
    __shared__ uint tl[16 * (HSTRIDE / 2)];     // t tile, 68 uints/row
    __shared__ int  sflags[2];
    ushort* hl = (ushort*)&smem[0][0];          // hidden tile overlay (post-sync)

    const int tid  = threadIdx.x;
    const int wave = tid >> 6;
    const int lane = tid & 63;
    const int m    = lane & 15;
    const int quad = lane >> 4;
    const int node0 = blockIdx.x * 16;
    const int n0w   = node0 + wave * 4;

    const ushort* w1h = (const ushort*)(ws + WH_OFF);
    const ushort* w2h = w1h + 16384;
    const uint*   xh  = (const uint*)(ws + XH_OFF);
    const char*   xhb = (const char*)xh;
    const uint*   bkt8 = (const uint*)(ws + BKT8_OFF);
    const uint    lane4 = (uint)lane * 4;
    const uint    sub16 = (uint)(lane & 15) * 16;
    char*         wbuf  = smem[wave];
    uint*         ebw   = (uint*)(wbuf + SLOTS * 256);   // 4 x 64-entry compact lists

    // ---- counts for the wave's 4 nodes, loaded once (lanes 0..31) ----
    int rawc = 0;
    if (lane < 32)
        rawc = ws[CNT8_OFF + (size_t)(lane & 7) * NN + (n0w + (lane >> 3))] + 1;
    const unsigned long long ex_mask  = __ballot(lane < 32 && rawc > 8);
    const unsigned long long ovf_mask = __ballot(lane < 32 && rawc > SCAP);

    // ---- compaction: ballot + mbcnt + ds_permute, per node ----
    const int xcd8 = lane >> 3, idx8 = lane & 7;
    int ecnt[4];
    #pragma unroll
    for (int j = 0; j < 4; ++j) {
        int n = n0w + j;
        int myc = __shfl(rawc, j * 8 + xcd8);            // sub-bucket count
        bool valid = idx8 < ((myc < 8) ? myc : 8);
        uint e = 0xffffffffu;
        if (valid) e = bkt8[((size_t)xcd8 * NN + n) * SCAP + idx8];
        unsigned long long vm = __ballot(valid);
        uint slot = valid ? mbcnt64(vm) : (63u - mbcnt64(~vm));
        uint ed = (uint)__builtin_amdgcn_ds_permute((int)(slot * 4), (int)e);
        ebw[j * 64 + lane] = ed;
        ecnt[j] = __popcll(vm);
    }

    // self-row prefetch
    uint xv[4];
    #pragma unroll
    for (int j = 0; j < 4; ++j)
        xv[j] = xh[(size_t)(n0w + j) * 64 + lane];

    block_probe(xraw, eraw, sflags);
    const int f32 = sflags[0];
    const float eps1 = 1.0f + (f32 ? ((const float*)epsraw)[0] : b2f(epsraw[0]));

    #pragma unroll
    for (int j = 0; j < 4; ++j) {
        int nl = wave * 4 + j;
        int n  = node0 + nl;
        int cnt = ecnt[j];
        const uint* ewp = ebw + j * 64;

        // prior node's ds_reads / this node's list writes must be done
        asm volatile("s_waitcnt lgkmcnt(0)" ::: "memory");

        // issue: 6 grouped stages; lane group (lane>>4) covers row 4g+grp
        #pragma unroll
        for (int g = 0; g < SLOTS / 4; ++g) {
            uint slot = (uint)(g * 4) + (uint)(lane >> 4);
            uint e0 = ewp[slot];                             // broadcast ds_read
            e0 = (slot < (uint)cnt) ? e0 : 0xffffffffu;
            uint row = e0 & 0xffffu;
            row = (row < NN) ? row : NN;                     // pad -> dedicated row NN
            gload_lds16(xhb + ((size_t)row << 8) + sub16, wbuf + g * 1024);
        }

        uint mm[4] = {~0u, ~0u, ~0u, ~0u};                   // packed fp16 NaN,NaN

        // first half: rows 0..11 after vmcnt(3)
        asm volatile("s_waitcnt vmcnt(3)" ::: "memory");
        #pragma unroll
        for (int g = 0; g < 3; ++g) {
            uint4 e4 = *(const uint4*)(ewp + g * 4);
            #pragma unroll
            for (int t = 0; t < 4; ++t) {
                int u = g * 4 + t;
                uint e0 = (u < cnt) ? ((const uint*)&e4)[t] : 0xffffffffu;
                uint v = *(const uint*)(wbuf + u * 256 + lane4);
                uint p;
                asm("v_pk_mul_f16 %0, %1, %2 op_sel:[0,1] op_sel_hi:[1,1]"
                    : "=v"(p) : "v"(v), "v"(e0));
                asm("v_pk_max_f16 %0, %0, %1" : "+v"(mm[u & 3]) : "v"(p));
            }
        }
        // second half: rows 12..23 after vmcnt(0)
        asm volatile("s_waitcnt vmcnt(0)" ::: "memory");
        #pragma unroll
        for (int g = 3; g < SLOTS / 4; ++g) {
            uint4 e4 = *(const uint4*)(ewp + g * 4);
            #pragma unroll
            for (int t = 0; t < 4; ++t) {
                int u = g * 4 + t;
                uint e0 = (u < cnt) ? ((const uint*)&e4)[t] : 0xffffffffu;
                uint v = *(const uint*)(wbuf + u * 256 + lane4);
                uint p;
                asm("v_pk_mul_f16 %0, %1, %2 op_sel:[0,1] op_sel_hi:[1,1]"
                    : "=v"(p) : "v"(v), "v"(e0));
                asm("v_pk_max_f16 %0, %0, %1" : "+v"(mm[u & 3]) : "v"(p));
            }
        }
        // remainder entries 24..cnt from compact list (P(deg>24) ~ 2.6%)
        for (int i = SLOTS; i < cnt; ++i) {
            uint e0 = ewp[i];
            uint v  = *(const uint*)(xhb + ((size_t)(e0 & 0xffffu) << 8) + lane4);
            uint p;
            asm("v_pk_mul_f16 %0, %1, %2 op_sel:[0,1] op_sel_hi:[1,1]"
                : "=v"(p) : "v"(v), "v"(e0));
            asm("v_pk_max_f16 %0, %0, %1" : "+v"(mm[0]) : "v"(p));
        }
        // sub-entries with idx>=8 (rare, wave-uniform branch)
        if ((ex_mask >> (j * 8)) & 0xffull) {
            for (int k2 = 0; k2 < 8; ++k2) {
                int rr = __shfl(rawc, j * 8 + k2);
                int c2 = (rr < SCAP) ? rr : SCAP;
                for (int o2 = 8; o2 < c2; ++o2) {
                    uint e0 = bkt8[((size_t)k2 * NN + n) * SCAP + o2];
                    uint v  = *(const uint*)(xhb + ((size_t)(e0 & 0xffffu) << 8) + lane4);
                    uint p;
                    asm("v_pk_mul_f16 %0, %1, %2 op_sel:[0,1] op_sel_hi:[1,1]"
                        : "=v"(p) : "v"(v), "v"(e0));
                    asm("v_pk_max_f16 %0, %0, %1" : "+v"(mm[0]) : "v"(p));
                }
            }
        }

        // reduce 4 -> 1
        asm("v_pk_max_f16 %0, %0, %1" : "+v"(mm[0]) : "v"(mm[1]));
        asm("v_pk_max_f16 %0, %0, %1" : "+v"(mm[2]) : "v"(mm[3]));
        asm("v_pk_max_f16 %0, %0, %1" : "+v"(mm[0]) : "v"(mm[2]));
        float mx = h2f((ushort)(mm[0] & 0xffffu));
        float my = h2f((ushort)(mm[0] >> 16));

        // sub-bucket overflow entries (very rare)
        if ((ovf_mask >> (j * 8)) & 0xffull) {
            int novf = ws[OVF_CNT_OFF] + 1;
            if (novf > OVF_CAP) novf = OVF_CAP;
            for (int o = 0; o < novf; ++o) {
                if (ws[OVF_OFF + 2 * o] == n) {
                    uint e0 = (uint)ws[OVF_OFF + 2 * o + 1];
                    uint v  = xh[(size_t)(e0 & 0xffffu) * 64 + lane];
                    float w = h2f((ushort)(e0 >> 16));
                    mx = fmaxf(mx, h2f((ushort)(v & 0xffffu)) * w);
                    my = fmaxf(my, h2f((ushort)(v >> 16)) * w);
                }
            }
        }
        if (ecnt[j] == 0) { mx = 0.f; my = 0.f; }            // isolated node -> 0

        // self term from prefetched row
        float t0 = eps1 * h2f((ushort)(xv[j] & 0xffffu)) + mx;
        float t1 = eps1 * h2f((ushort)(xv[j] >> 16)) + my;
        tl[nl * (HSTRIDE / 2) + lane] = (uint)f2h(t0) | ((uint)f2h(t1) << 16);
    }
    __syncthreads();

    // A frags from LDS t tile
    half8 a[4];
    {
        const ushort* arow = (const ushort*)tl + m * HSTRIDE + quad * 8;
        #pragma unroll
        for (int kb = 0; kb < 4; ++kb) a[kb] = *(const half8*)(arow + kb * 32);
    }

    // GEMM1 + bias + LeakyReLU -> hl (overlaid on gather buffer)
    #pragma unroll
    for (int t = 0; t < 2; ++t) {
        int ct = wave * 2 + t;
        float4v c = {0.f, 0.f, 0.f, 0.f};
        const ushort* brow = w1h + (size_t)(ct * 16 + m) * 128 + quad * 8;
        #pragma unroll
        for (int kb = 0; kb < 4; ++kb)
            c = __builtin_amdgcn_mfma_f32_16x16x32_f16(a[kb], *(const half8*)(brow + kb * 32), c, 0, 0, 0);
        float bias = f32 ? ((const float*)b1raw)[ct * 16 + m] : b2f(b1raw[ct * 16 + m]);
        #pragma unroll
        for (int r = 0; r < 4; ++r) {
            float v = c[r] + bias;
            v = (v >= 0.f) ? v : 0.01f * v;
            hl[(quad * 4 + r) * HSTRIDE + ct * 16 + m] = f2h(v);
        }
    }
    __syncthreads();

    // A frags for GEMM2 from hl
    half8 ah[4];
    {
        const ushort* hrow = hl + m * HSTRIDE + quad * 8;
        #pragma unroll
        for (int kb = 0; kb < 4; ++kb) ah[kb] = *(const half8*)(hrow + kb * 32);
    }

    // GEMM2 + bias -> out
    #pragma unroll
    for (int t = 0; t < 2; ++t) {
        int ct = wave * 2 + t;
        float4v c = {0.f, 0.f, 0.f, 0.f};
        const ushort* brow = w2h + (size_t)(ct * 16 + m) * 128 + quad * 8;
        #pragma unroll
        for (int kb = 0; kb < 4; ++kb)
            c = __builtin_amdgcn_mfma_f32_16x16x32_f16(ah[kb], *(const half8*)(brow + kb * 32), c, 0, 0, 0);
        float bias = f32 ? ((const float*)b2raw)[ct * 16 + m] : b2f(b2raw[ct * 16 + m]);
        #pragma unroll
        for (int r = 0; r < 4; ++r) {
            float v = c[r] + bias;
            size_t o = (size_t)(node0 + quad * 4 + r) * 128 + ct * 16 + m;
            if (f32) ((float*)outraw)[o] = v;
            else     outraw[o] = f2b(v);
        }
    }
}

// ================= host =================
extern "C" void kernel_launch(void* const* d_in, const int* in_sizes, int n_in,
                              void* d_out, int out_size, void* d_ws, size_t ws_size,
                              hipStream_t stream) {
    const uint16_t* x    = (const uint16_t*)d_in[0];
    const int*      eidx = (const int*)     d_in[1];
    const uint16_t* ew   = (const uint16_t*)d_in[2];
    const uint16_t* w1   = (const uint16_t*)d_in[3];
    const uint16_t* b1   = (const uint16_t*)d_in[4];
    const uint16_t* w2   = (const uint16_t*)d_in[5];
    const uint16_t* b2   = (const uint16_t*)d_in[6];
    const uint16_t* eps  = (const uint16_t*)d_in[7];
    uint16_t*       out  = (uint16_t*)d_out;
    int* ws = (int*)d_ws;

    // init 8 per-XCD counter arrays (+ overflow counter) to -1
    hipMemsetAsync((char*)d_ws + (size_t)CNT8_OFF * 4, 0xFF,
                   ((size_t)NXCD * NN + 1) * 4, stream);
    prep_fill_kernel<<<FILL_BLKS + PX_BLKS + PW_BLKS, 256, 0, stream>>>(
        x, eidx, ew, w1, w2, ws);
    gmlp_kernel<<<NN / 16, 256, 0, stream>>>(x, eidx, b1, b2, eps, ws, out);
}

// Round 9
// 196.289 us; speedup vs baseline: 1.0498x; 1.0019x over previous
//
#include <hip/hip_runtime.h>
#include <stdint.h>

#define NN 50000
#define NE 800000
#define D  128
#define CAP 64                            // compacted entries staged per node (8/XCD x 8)
#define SCAP 10                           // per-XCD sub-bucket cap (deg/XCD ~ Poisson(2))
#define NXCD 8
#define OVF_CAP 65536

// ---------------- ws layout (int offsets) ----------------
// Per-XCD counters init to -1 via 0xFF memset (slot = atomicAdd()+1), filled
// with XCD-LOCAL (workgroup-scope) atomics: each XCD's CUs are the only
// writers of their region, so the L2-local RMW is atomic; cross-kernel
// visibility via the dispatch-boundary L2 writeback. Sub-buckets UNINIT.
#define CNT8_OFF    64                    // 8*NN per-XCD counters
#define OVF_CNT_OFF (CNT8_OFF + NXCD * NN)          // 400064
#define OVF_OFF     (OVF_CNT_OFF + 4)               // 400068: OVF_CAP pairs (dst, entry)
#define BKT8_OFF    531200                // 8*NN*SCAP entries: (w_fp16<<16)|src
#define XH_OFF      (BKT8_OFF + NXCD * NN * SCAP)   // 4531200: x fp16 pairs, NN+1 rows (row NN = pad)
#define WH_OFF      (XH_OFF + (NN + 1) * (D / 2))   // 7731264: w1+w2 fp16
// high-water: 7,747,648 ints = 31.0 MB (< 32.4 MB proven available)

#define HSTRIDE 136                       // LDS row stride in ushorts (272 B, 2-way banks = free)
#define SLOTS   16                        // staged row-gathers per pass (2nd pass if deg>16)
#define WLDS    (SLOTS * 256 + 1024)      // per-wave LDS: 16 value rows + 4x64-entry compact lists
// LDS block: 4*5120 + 4360 = 24.8 KB -> 6 blocks/CU (~24 waves; was 4 blocks
// at 33 KB). The occupancy lever is the one untested axis on the gather wall.

// fused prep+fill block ranges
#define FILL_BLKS 3125                    // NE/256 (1 edge/thread)
#define PX_BLKS   6250                    // NN*D/1024
#define PW_BLKS   32

typedef _Float16 half8 __attribute__((ext_vector_type(8)));
typedef __attribute__((ext_vector_type(4))) float float4v;

// ---------------- dtype helpers ----------------
__device__ __forceinline__ float b2f(uint16_t u) {
    union { uint32_t u; float f; } v; v.u = ((uint32_t)u) << 16; return v.f;
}
__device__ __forceinline__ uint16_t f2b(float f) {
    union { float f; uint32_t u; } v; v.f = f;
    uint32_t r = v.u + 0x7fffu + ((v.u >> 16) & 1u);   // RNE
    return (uint16_t)(r >> 16);
}
__device__ __forceinline__ ushort f2h(float f) {
    union { _Float16 h; ushort u; } v; v.h = (_Float16)f; return v.u;   // v_cvt_f16_f32 (RNE)
}
__device__ __forceinline__ float h2f(ushort u) {
    union { ushort u; _Float16 h; } v; v.u = u; return (float)v.h;
}

// async global->LDS, 16 B/lane: LDS dest = uniform base + lane*16 (1 KB =
// four 256 B rows); global src per-lane. Counts in vmcnt.
__device__ __forceinline__ void gload_lds16(const void* g, void* l) {
    __builtin_amdgcn_global_load_lds(
        (const __attribute__((address_space(1))) void*)g,
        (__attribute__((address_space(3))) void*)l, 16, 0, 0);
}

__device__ __forceinline__ uint mbcnt64(unsigned long long m) {
    return __builtin_amdgcn_mbcnt_hi((uint)(m >> 32),
           __builtin_amdgcn_mbcnt_lo((uint)m, 0u));
}

// ---------------- per-block inline dtype probe (load-bearing; rounds 2-9) ----------------
__device__ __forceinline__ void block_probe(const uint16_t* __restrict__ xraw,
                                            const int* __restrict__ eraw,
                                            int* sflags) {
    int t = threadIdx.x;
    if (t < 64) {                                   // wave 0 only
        float v0 = b2f(xraw[2 * t]);
        float v1 = b2f(xraw[2 * t + 1]);
        int bad = (!(v0 > -1e4f && v0 < 1e4f)) || (!(v1 > -1e4f && v1 < 1e4f));
        unsigned long long bm = __ballot(bad);
        int nz = (t < 32) ? (eraw[2 * t + 1] != 0) : 0;
        unsigned long long im = __ballot(nz);
        if (t == 0) { sflags[0] = bm ? 1 : 0; sflags[1] = im ? 0 : 1; }
    }
    __syncthreads();
}

// ---------------- fused fill + prep_x + prep_w (unchanged from R8) ----------------
__global__ __launch_bounds__(256) void prep_fill_kernel(
    const uint16_t* __restrict__ xraw,
    const int*      __restrict__ eraw,
    const uint16_t* __restrict__ ewraw,
    const uint16_t* __restrict__ w1raw,
    const uint16_t* __restrict__ w2raw,
    int* __restrict__ ws)
{
    __shared__ int sflags[2];
    block_probe(xraw, eraw, sflags);
    const int f32 = sflags[0], i64 = sflags[1];

    int bid = blockIdx.x;
    if (bid < FILL_BLKS) {
        // ---- edge fill: XCD-local counter atomic + sub-bucket write ----
        uint xcd;
        asm volatile("s_getreg_b32 %0, hwreg(HW_REG_XCC_ID)" : "=s"(xcd));
        xcd &= (NXCD - 1);

        int e = bid * 256 + threadIdx.x;
        int src, dst;
        if (i64) {
            const long long* e64 = (const long long*)eraw;
            src = (int)e64[e];
            dst = (int)e64[NE + e];
        } else {
            src = eraw[e];
            dst = eraw[NE + e];
        }
        if ((unsigned)src >= NN || (unsigned)dst >= NN) return;
        uint w = f32 ? (uint)f2h(((const float*)ewraw)[e]) : (uint)f2h(b2f(ewraw[e]));
        uint entry = (w << 16) | (uint)src;
        // L2-local RMW: only this XCD's CUs touch cnt8[xcd][*]
        int slot = __hip_atomic_fetch_add(ws + CNT8_OFF + (size_t)xcd * NN + dst, 1,
                                          __ATOMIC_RELAXED, __HIP_MEMORY_SCOPE_WORKGROUP) + 1;
        if (slot < SCAP) {
            ((uint*)(ws + BKT8_OFF))[((size_t)xcd * NN + dst) * SCAP + slot] = entry;
        } else {
            int o = atomicAdd(ws + OVF_CNT_OFF, 1) + 1;      // rare: device scope fine
            if (o < OVF_CAP) {
                ws[OVF_OFF + 2 * o]     = dst;
                ws[OVF_OFF + 2 * o + 1] = (int)entry;
            }
        }
    } else if (bid < FILL_BLKS + PX_BLKS) {
        // ---- x -> fp16 table ----
        int i4 = ((bid - FILL_BLKS) * 256 + threadIdx.x) * 4;   // covers NN*D exactly
        ushort* dst = (ushort*)(ws + XH_OFF);
        if (f32) {
            float4 v = *(const float4*)((const float*)xraw + i4);
            ushort4 o; o.x = f2h(v.x); o.y = f2h(v.y); o.z = f2h(v.z); o.w = f2h(v.w);
            *(ushort4*)(dst + i4) = o;
        } else {
            ushort4 v = *(const ushort4*)(xraw + i4);
            ushort4 o; o.x = f2h(b2f(v.x)); o.y = f2h(b2f(v.y));
            o.z = f2h(b2f(v.z)); o.w = f2h(b2f(v.w));
            *(ushort4*)(dst + i4) = o;
        }
    } else {
        // ---- w1,w2 -> fp16 table ----
        int i4 = ((bid - FILL_BLKS - PX_BLKS) * 256 + threadIdx.x) * 4; // 0..32764
        const uint16_t* src = (i4 < 16384) ? w1raw : w2raw;
        int off = i4 & 16383;
        ushort* dst = (ushort*)(ws + WH_OFF);
        if (f32) {
            float4 v = *(const float4*)((const float*)src + off);
            ushort4 o; o.x = f2h(v.x); o.y = f2h(v.y); o.z = f2h(v.z); o.w = f2h(v.w);
            *(ushort4*)(dst + i4) = o;
        } else {
            ushort4 v = *(const ushort4*)(src + off);
            ushort4 o; o.x = f2h(b2f(v.x)); o.y = f2h(b2f(v.y));
            o.z = f2h(b2f(v.z)); o.w = f2h(b2f(v.w));
            *(ushort4*)(dst + i4) = o;
        }
    }
}

// ---------------- fused gather-max + MFMA MLP ----------------
// 16 nodes/block, 4 waves, 6 blocks/CU (24.8 KB LDS). Compaction as R8
// (ballot+mbcnt+ds_permute). Per node: pass A stages 16 rows (4x 16B-DMA),
// consume; if cnt>16 (wave-uniform: ecnt from ballot) pass B stages rows
// 16..31 into the same buffer; deg>32 (P~1.3e-4) serial from compact list.
__global__ __launch_bounds__(256, 6) void gmlp_kernel(
    const uint16_t* __restrict__ xraw,
    const int*      __restrict__ eraw,
    const uint16_t* __restrict__ b1raw,
    const uint16_t* __restrict__ b2raw,
    const uint16_t* __restrict__ epsraw,
    const int* __restrict__ ws,
    uint16_t* __restrict__ outraw)
{
    __shared__ char smem[4][WLDS];              // per-wave: [0,4096) value rows, [4096,5120) compact lists
    __shared__ uint tl[16 * (HSTRIDE / 2)];     // t tile, 68 uints/row
    __shared__ int  sflags[2];
    ushort* hl = (ushort*)&smem[0][0];          // hidden tile overlay (post-sync; 4352 B < WLDS)

    const int tid  = threadIdx.x;
    const int wave = tid >> 6;
    const int lane = tid & 63;
    const int m    = lane & 15;
    const int quad = lane >> 4;
    const int node0 = blockIdx.x * 16;
    const int n0w   = node0 + wave * 4;

    const ushort* w1h = (const ushort*)(ws + WH_OFF);
    const ushort* w2h = w1h + 16384;
    const uint*   xh  = (const uint*)(ws + XH_OFF);
    const char*   xhb = (const char*)xh;
    const uint*   bkt8 = (const uint*)(ws + BKT8_OFF);
    const uint    lane4 = (uint)lane * 4;
    const uint    sub16 = (uint)(lane & 15) * 16;
    char*         wbuf  = smem[wave];
    uint*         ebw   = (uint*)(wbuf + SLOTS * 256);   // 4 x 64-entry compact lists

    // ---- counts for the wave's 4 nodes, loaded once (lanes 0..31) ----
    int rawc = 0;
    if (lane < 32)
        rawc = ws[CNT8_OFF + (size_t)(lane & 7) * NN + (n0w + (lane >> 3))] + 1;
    const unsigned long long ex_mask  = __ballot(lane < 32 && rawc > 8);
    const unsigned long long ovf_mask = __ballot(lane < 32 && rawc > SCAP);

    // ---- compaction: ballot + mbcnt + ds_permute, per node ----
    const int xcd8 = lane >> 3, idx8 = lane & 7;
    int ecnt[4];
    #pragma unroll
    for (int j = 0; j < 4; ++j) {
        int n = n0w + j;
        int myc = __shfl(rawc, j * 8 + xcd8);            // sub-bucket count
        bool valid = idx8 < ((myc < 8) ? myc : 8);
        uint e = 0xffffffffu;
        if (valid) e = bkt8[((size_t)xcd8 * NN + n) * SCAP + idx8];
        unsigned long long vm = __ballot(valid);
        uint slot = valid ? mbcnt64(vm) : (63u - mbcnt64(~vm));
        uint ed = (uint)__builtin_amdgcn_ds_permute((int)(slot * 4), (int)e);
        ebw[j * 64 + lane] = ed;
        ecnt[j] = __popcll(vm);
    }

    // self-row prefetch
    uint xv[4];
    #pragma unroll
    for (int j = 0; j < 4; ++j)
        xv[j] = xh[(size_t)(n0w + j) * 64 + lane];

    block_probe(xraw, eraw, sflags);
    const int f32 = sflags[0];
    const float eps1 = 1.0f + (f32 ? ((const float*)epsraw)[0] : b2f(epsraw[0]));

    #pragma unroll
    for (int j = 0; j < 4; ++j) {
        int nl = wave * 4 + j;
        int n  = node0 + nl;
        int cnt = ecnt[j];                               // wave-uniform (from ballot)
        const uint* ewp = ebw + j * 64;

        // prior node's ds_reads / this node's list writes must be done
        asm volatile("s_waitcnt lgkmcnt(0)" ::: "memory");

        // pass A: stage rows 0..15 (4 x 16B-DMA; lane group covers row 4g+grp)
        #pragma unroll
        for (int g = 0; g < 4; ++g) {
            uint slot = (uint)(g * 4) + (uint)(lane >> 4);
            uint e0 = ewp[slot];                         // broadcast ds_read
            e0 = (slot < (uint)cnt) ? e0 : 0xffffffffu;
            uint row = e0 & 0xffffu;
            row = (row < NN) ? row : NN;                 // pad -> dedicated row NN
            gload_lds16(xhb + ((size_t)row << 8) + sub16, wbuf + g * 1024);
        }

        uint mm[4] = {~0u, ~0u, ~0u, ~0u};               // packed fp16 NaN,NaN

        // consume rows 0..7 after vmcnt(2), 8..15 after vmcnt(0)
        asm volatile("s_waitcnt vmcnt(2)" ::: "memory");
        #pragma unroll
        for (int g = 0; g < 2; ++g) {
            uint4 e4 = *(const uint4*)(ewp + g * 4);
            #pragma unroll
            for (int t = 0; t < 4; ++t) {
                int u = g * 4 + t;
                uint e0 = (u < cnt) ? ((const uint*)&e4)[t] : 0xffffffffu;
                uint v = *(const uint*)(wbuf + u * 256 + lane4);
                uint p;
                asm("v_pk_mul_f16 %0, %1, %2 op_sel:[0,1] op_sel_hi:[1,1]"
                    : "=v"(p) : "v"(v), "v"(e0));
                asm("v_pk_max_f16 %0, %0, %1" : "+v"(mm[u & 3]) : "v"(p));
            }
        }
        asm volatile("s_waitcnt vmcnt(0)" ::: "memory");
        #pragma unroll
        for (int g = 2; g < 4; ++g) {
            uint4 e4 = *(const uint4*)(ewp + g * 4);
            #pragma unroll
            for (int t = 0; t < 4; ++t) {
                int u = g * 4 + t;
                uint e0 = (u < cnt) ? ((const uint*)&e4)[t] : 0xffffffffu;
                uint v = *(const uint*)(wbuf + u * 256 + lane4);
                uint p;
                asm("v_pk_mul_f16 %0, %1, %2 op_sel:[0,1] op_sel_hi:[1,1]"
                    : "=v"(p) : "v"(v), "v"(e0));
                asm("v_pk_max_f16 %0, %0, %1" : "+v"(mm[u & 3]) : "v"(p));
            }
        }

        // pass B (deg>16; ~46% of nodes; wave-uniform branch): rows 16..31
        if (cnt > SLOTS) {
            asm volatile("s_waitcnt lgkmcnt(0)" ::: "memory");   // pass-A ds_reads done
            #pragma unroll
            for (int g = 0; g < 4; ++g) {
                uint slot = (uint)(SLOTS + g * 4) + (uint)(lane >> 4);
                uint e0 = ewp[slot];
                e0 = (slot < (uint)cnt) ? e0 : 0xffffffffu;
                uint row = e0 & 0xffffu;
                row = (row < NN) ? row : NN;
                gload_lds16(xhb + ((size_t)row << 8) + sub16, wbuf + g * 1024);
            }
            asm volatile("s_waitcnt vmcnt(0)" ::: "memory");
            #pragma unroll
            for (int g = 0; g < 4; ++g) {
                uint4 e4 = *(const uint4*)(ewp + SLOTS + g * 4);
                #pragma unroll
                for (int t = 0; t < 4; ++t) {
                    int u = g * 4 + t;
                    uint e0 = ((SLOTS + u) < cnt) ? ((const uint*)&e4)[t] : 0xffffffffu;
                    uint v = *(const uint*)(wbuf + u * 256 + lane4);
                    uint p;
                    asm("v_pk_mul_f16 %0, %1, %2 op_sel:[0,1] op_sel_hi:[1,1]"
                        : "=v"(p) : "v"(v), "v"(e0));
                    asm("v_pk_max_f16 %0, %0, %1" : "+v"(mm[u & 3]) : "v"(p));
                }
            }
            // entries 32..cnt (P(deg>32) ~ 1.3e-4): serial from compact list
            for (int i = 2 * SLOTS; i < cnt; ++i) {
                uint e0 = ewp[i];
                uint v  = *(const uint*)(xhb + ((size_t)(e0 & 0xffffu) << 8) + lane4);
                uint p;
                asm("v_pk_mul_f16 %0, %1, %2 op_sel:[0,1] op_sel_hi:[1,1]"
                    : "=v"(p) : "v"(v), "v"(e0));
                asm("v_pk_max_f16 %0, %0, %1" : "+v"(mm[0]) : "v"(p));
            }
        }
        // sub-entries with idx>=8 (rare, wave-uniform branch)
        if ((ex_mask >> (j * 8)) & 0xffull) {
            for (int k2 = 0; k2 < 8; ++k2) {
                int rr = __shfl(rawc, j * 8 + k2);
                int c2 = (rr < SCAP) ? rr : SCAP;
                for (int o2 = 8; o2 < c2; ++o2) {
                    uint e0 = bkt8[((size_t)k2 * NN + n) * SCAP + o2];
                    uint v  = *(const uint*)(xhb + ((size_t)(e0 & 0xffffu) << 8) + lane4);
                    uint p;
                    asm("v_pk_mul_f16 %0, %1, %2 op_sel:[0,1] op_sel_hi:[1,1]"
                        : "=v"(p) : "v"(v), "v"(e0));
                    asm("v_pk_max_f16 %0, %0, %1" : "+v"(mm[0]) : "v"(p));
                }
            }
        }

        // reduce 4 -> 1
        asm("v_pk_max_f16 %0, %0, %1" : "+v"(mm[0]) : "v"(mm[1]));
        asm("v_pk_max_f16 %0, %0, %1" : "+v"(mm[2]) : "v"(mm[3]));
        asm("v_pk_max_f16 %0, %0, %1" : "+v"(mm[0]) : "v"(mm[2]));
        float mx = h2f((ushort)(mm[0] & 0xffffu));
        float my = h2f((ushort)(mm[0] >> 16));

        // sub-bucket overflow entries (very rare)
        if ((ovf_mask >> (j * 8)) & 0xffull) {
            int novf = ws[OVF_CNT_OFF] + 1;
            if (novf > OVF_CAP) novf = OVF_CAP;
            for (int o = 0; o < novf; ++o) {
                if (ws[OVF_OFF + 2 * o] == n) {
                    uint e0 = (uint)ws[OVF_OFF + 2 * o + 1];
                    uint v  = xh[(size_t)(e0 & 0xffffu) * 64 + lane];
                    float w = h2f((ushort)(e0 >> 16));
                    mx = fmaxf(mx, h2f((ushort)(v & 0xffffu)) * w);
                    my = fmaxf(my, h2f((ushort)(v >> 16)) * w);
                }
            }
        }
        if (ecnt[j] == 0) { mx = 0.f; my = 0.f; }        // isolated node -> 0

        // self term from prefetched row
        float t0 = eps1 * h2f((ushort)(xv[j] & 0xffffu)) + mx;
        float t1 = eps1 * h2f((ushort)(xv[j] >> 16)) + my;
        tl[nl * (HSTRIDE / 2) + lane] = (uint)f2h(t0) | ((uint)f2h(t1) << 16);
    }
    __syncthreads();

    // A frags from LDS t tile
    half8 a[4];
    {
        const ushort* arow = (const ushort*)tl + m * HSTRIDE + quad * 8;
        #pragma unroll
        for (int kb = 0; kb < 4; ++kb) a[kb] = *(const half8*)(arow + kb * 32);
    }

    // GEMM1 + bias + LeakyReLU -> hl (overlaid on gather buffer)
    #pragma unroll
    for (int t = 0; t < 2; ++t) {
        int ct = wave * 2 + t;
        float4v c = {0.f, 0.f, 0.f, 0.f};
        const ushort* brow = w1h + (size_t)(ct * 16 + m) * 128 + quad * 8;
        #pragma unroll
        for (int kb = 0; kb < 4; ++kb)
            c = __builtin_amdgcn_mfma_f32_16x16x32_f16(a[kb], *(const half8*)(brow + kb * 32), c, 0, 0, 0);
        float bias = f32 ? ((const float*)b1raw)[ct * 16 + m] : b2f(b1raw[ct * 16 + m]);
        #pragma unroll
        for (int r = 0; r < 4; ++r) {
            float v = c[r] + bias;
            v = (v >= 0.f) ? v : 0.01f * v;
            hl[(quad * 4 + r) * HSTRIDE + ct * 16 + m] = f2h(v);
        }
    }
    __syncthreads();

    // A frags for GEMM2 from hl
    half8 ah[4];
    {
        const ushort* hrow = hl + m * HSTRIDE + quad * 8;
        #pragma unroll
        for (int kb = 0; kb < 4; ++kb) ah[kb] = *(const half8*)(hrow + kb * 32);
    }

    // GEMM2 + bias -> out
    #pragma unroll
    for (int t = 0; t < 2; ++t) {
        int ct = wave * 2 + t;
        float4v c = {0.f, 0.f, 0.f, 0.f};
        const ushort* brow = w2h + (size_t)(ct * 16 + m) * 128 + quad * 8;
        #pragma unroll
        for (int kb = 0; kb < 4; ++kb)
            c = __builtin_amdgcn_mfma_f32_16x16x32_f16(ah[kb], *(const half8*)(brow + kb * 32), c, 0, 0, 0);
        float bias = f32 ? ((const float*)b2raw)[ct * 16 + m] : b2f(b2raw[ct * 16 + m]);
        #pragma unroll
        for (int r = 0; r < 4; ++r) {
            float v = c[r] + bias;
            size_t o = (size_t)(node0 + quad * 4 + r) * 128 + ct * 16 + m;
            if (f32) ((float*)outraw)[o] = v;
            else     outraw[o] = f2b(v);
        }
    }
}

// ================= host =================
extern "C" void kernel_launch(void* const* d_in, const int* in_sizes, int n_in,
                              void* d_out, int out_size, void* d_ws, size_t ws_size,
                              hipStream_t stream) {
    const uint16_t* x    = (const uint16_t*)d_in[0];
    const int*      eidx = (const int*)     d_in[1];
    const uint16_t* ew   = (const uint16_t*)d_in[2];
    const uint16_t* w1   = (const uint16_t*)d_in[3];
    const uint16_t* b1   = (const uint16_t*)d_in[4];
    const uint16_t* w2   = (const uint16_t*)d_in[5];
    const uint16_t* b2   = (const uint16_t*)d_in[6];
    const uint16_t* eps  = (const uint16_t*)d_in[7];
    uint16_t*       out  = (uint16_t*)d_out;
    int* ws = (int*)d_ws;

    // init 8 per-XCD counter arrays (+ overflow counter) to -1
    hipMemsetAsync((char*)d_ws + (size_t)CNT8_OFF * 4, 0xFF,
                   ((size_t)NXCD * NN + 1) * 4, stream);
    prep_fill_kernel<<<FILL_BLKS + PX_BLKS + PW_BLKS, 256, 0, stream>>>(
        x, eidx, ew, w1, w2, ws);
    gmlp_kernel<<<NN / 16, 256, 0, stream>>>(x, eidx, b1, b2, eps, ws, out);
}